// Round 9
// baseline (13734.731 us; speedup 1.0000x reference)
//
#include <hip/hip_runtime.h>
#include <math.h>

#define T_STEPS 512
#define IN_DIM  17
#define HID     512
#define LAT     256
#define BT      16
#define NTH     512
#define CHUNK   4

typedef __attribute__((ext_vector_type(8))) _Float16 half8;
typedef __attribute__((ext_vector_type(4))) float    f32x4;

// ---------------- workspace layout (byte offsets, 16B-aligned) ----------
// hbuf0/1 : h double buffer, SLICE-MAJOR: [8 g][32 ss][512 row][16] fp16
#define OFF_HB0   0
#define OFF_HB1   4194304
#define OFF_LAT   8388608
#define OFF_WG    16777216
#define OFF_W2P   19136512
#define OFF_W1P   19267584
#define OFF_HEADP 19283968
#define OFF_W256  19300352
#define OFF_BCOMB 19306496
#define OFF_BHN   19312640
#define OFF_DT    19314688
#define OFF_CTR   19380224
// ctr region: stepslot uint[8][32] @+0 ; chunkslot uint[8][32] @+4096 ;
//             ticket uint[8] @+8192.

static __device__ inline unsigned short f2h(float f) {
    union { _Float16 h; unsigned short u; } cv;
    cv.h = (_Float16)f;
    return cv.u;
}

__global__ void pack_kernel(const float* __restrict__ enc_w1,
                            const float* __restrict__ enc_w2,
                            const float* __restrict__ w_ih,
                            const float* __restrict__ w_hh,
                            const float* __restrict__ b_ih,
                            const float* __restrict__ b_hh,
                            const float* __restrict__ q_w,
                            const float* __restrict__ v_w,
                            const float* __restrict__ c_w,
                            const float* __restrict__ h0,
                            unsigned char* __restrict__ ws) {
    unsigned short* wgP   = (unsigned short*)(ws + OFF_WG);
    unsigned short* w2P   = (unsigned short*)(ws + OFF_W2P);
    unsigned short* w1P   = (unsigned short*)(ws + OFF_W1P);
    unsigned short* headP = (unsigned short*)(ws + OFF_HEADP);
    unsigned short* hb0   = (unsigned short*)(ws + OFF_HB0);
    float* w256  = (float*)(ws + OFF_W256);
    float* bcomb = (float*)(ws + OFF_BCOMB);
    float* bhn   = (float*)(ws + OFF_BHN);
    unsigned int* ctr = (unsigned int*)(ws + OFF_CTR);

    const int tid = blockIdx.x * blockDim.x + threadIdx.x;
    const int stride = gridDim.x * blockDim.x;

    for (int idx = tid; idx < 32 * 24 * 3 * 64 * 8; idx += stride) {     // wgP
        int j = idx & 7, l = (idx >> 3) & 63;
        int r = idx >> 9;
        int g = r % 3; r /= 3;
        int kt = r % 24; int s = r / 24;
        int row = g * 512 + s * 16 + (l & 15);
        int kk  = ((l >> 4) & 3) * 8 + j;
        float v;
        if (kt < 8) v = w_ih[(size_t)row * 257 + (kt * 32 + kk)];
        else        v = w_hh[(size_t)row * 512 + ((kt - 8) * 32 + kk)];
        wgP[idx] = f2h(v);
    }
    for (int idx = tid; idx < 16 * 8 * 64 * 8; idx += stride) {          // w2P
        int j = idx & 7, l = (idx >> 3) & 63, kt = (idx >> 9) & 7, nt = idx >> 12;
        int n = nt * 16 + (l & 15);
        int k = kt * 32 + ((l >> 4) & 3) * 8 + j;
        w2P[idx] = f2h(enc_w2[(size_t)n * 256 + k]);
    }
    for (int idx = tid; idx < 16 * 64 * 8; idx += stride) {              // w1P
        int j = idx & 7, l = (idx >> 3) & 63, nt = idx >> 9;
        int n = nt * 16 + (l & 15);
        int k = ((l >> 4) & 3) * 8 + j;
        w1P[idx] = (k < IN_DIM) ? f2h(enc_w1[(size_t)n * IN_DIM + k]) : (unsigned short)0;
    }
    for (int idx = tid; idx < 16 * 64 * 8; idx += stride) {              // headP
        int j = idx & 7, l = (idx >> 3) & 63, kt = idx >> 9;
        int d = l & 15;
        int k = kt * 32 + ((l >> 4) & 3) * 8 + j;
        float v = 0.f;
        if (d < 4)       v = q_w[(size_t)d * HID + k];
        else if (d < 7)  v = v_w[(size_t)(d - 4) * HID + k];
        else if (d < 10) v = c_w[(size_t)(d - 7) * HID + k];
        headP[idx] = f2h(v);
    }
    for (int idx = tid; idx < 1536; idx += stride) {
        w256[idx]  = w_ih[(size_t)idx * 257 + 256];
        bcomb[idx] = (idx < 1024) ? (b_ih[idx] + b_hh[idx]) : b_ih[idx];
    }
    for (int idx = tid; idx < 512; idx += stride) bhn[idx] = b_hh[1024 + idx];
    for (int idx = tid; idx < 4096 * 512; idx += stride) {               // h0 -> hbuf0 (slice-major)
        int c  = idx & 15;
        int r  = (idx >> 4) & 511;
        int sg = idx >> 13;            // g*32 + ss
        int gg = sg >> 5, ss = sg & 31;
        hb0[idx] = f2h(h0[((size_t)(gg * 512 + r)) * 512 + ss * 16 + c]);
    }
    for (int idx = tid; idx < 4096; idx += stride) ctr[idx] = 0;         // slots + tickets
}

#define MFMA16(a, b, c) __builtin_amdgcn_mfma_f32_16x16x32_f16((a), (b), (c), 0, 0, 0)

// ---- tag-slot XCD-local barrier (full-group; used at chunk boundaries) ----
static __device__ inline void tag_arrive(unsigned int* slot, int ss, unsigned int tag) {
    __syncthreads();
    if (threadIdx.x == 0)
        __hip_atomic_store(slot + ss, tag, __ATOMIC_RELAXED, __HIP_MEMORY_SCOPE_AGENT);
}
static __device__ inline void tag_wait(unsigned int* slot, unsigned int tag) {
    if (threadIdx.x < 32) {
        const int lane = (int)threadIdx.x;
        unsigned int spins = 0;
        while (__hip_atomic_load(slot + lane, __ATOMIC_RELAXED, __HIP_MEMORY_SCOPE_AGENT) < tag) {
            __builtin_amdgcn_s_sleep(1);
            if (++spins > 50000000u) break;   // watchdog
        }
    }
    __syncthreads();
    asm volatile("buffer_inv sc0" ::: "memory");   // L1-only invalidate
}

// ---- per-kt producer gate: wave-scope wait for slots ss0, ss0+1 >= tag ----
// (no cache maintenance here: one buffer_inv per step precedes the h-loop,
//  and all reads of gated lines occur only after the tag is observed, so
//  every L1 fill of those lines is fresh.)
static __device__ inline void slot_wait2(const unsigned int* slot, int ss0,
                                         unsigned int tag, bool* dead) {
    if (*dead) return;
    const unsigned int* p = slot + ss0 + (int)(threadIdx.x & 1);
    unsigned int spins = 0;
    while (true) {
        unsigned int v = __hip_atomic_load(p, __ATOMIC_RELAXED, __HIP_MEMORY_SCOPE_AGENT);
        if (__all(v >= tag)) break;
        __builtin_amdgcn_s_sleep(1);
        if (++spins > 1000000u) { *dead = true; break; }   // watchdog
    }
    asm volatile("" ::: "memory");   // fence: no gated load hoisted above poll
}

__global__ __launch_bounds__(NTH, 2)
void imu_coop_kernel(const float* __restrict__ x,
                     const float* __restrict__ h0,
                     const float* __restrict__ enc_b1,
                     const float* __restrict__ enc_b2,
                     const float* __restrict__ q_b,
                     const float* __restrict__ v_b,
                     const float* __restrict__ c_b,
                     unsigned char* __restrict__ ws,
                     float* __restrict__ out)
{
    __shared__ __align__(16) unsigned short wgL[24 * 3 * 64 * 8];   // 73,728 B
    __shared__ __align__(16) unsigned short headL[16 * 64 * 8];     // 16,384 B
    __shared__ __align__(16) unsigned short xbf64[64][32];          //  4,096 B
    __shared__ __align__(16) unsigned short z1bf64[64][264];        // 33,792 B
    __shared__ __align__(16) float          sdotP[8][16][17];       //  8,704 B
    __shared__ float eb1L[256], eb2L[256];                          //  2,048 B
    __shared__ float dtL[512][4];                                   //  8,192 B
    __shared__ float xownL[2][4][16][4];                            //  2,048 B
    __shared__ float sdS[16][10];                                   //    640 B
    __shared__ int   s_slS;

    unsigned short* hb[2] = { (unsigned short*)(ws + OFF_HB0),
                              (unsigned short*)(ws + OFF_HB1) };
    unsigned short*       latbuf = (unsigned short*)(ws + OFF_LAT);
    const unsigned short* wgP    = (const unsigned short*)(ws + OFF_WG);
    const unsigned short* w2P    = (const unsigned short*)(ws + OFF_W2P);
    const unsigned short* w1P    = (const unsigned short*)(ws + OFF_W1P);
    const unsigned short* headP  = (const unsigned short*)(ws + OFF_HEADP);
    const float* w256g = (const float*)(ws + OFF_W256);
    const float* bcmg  = (const float*)(ws + OFF_BCOMB);
    const float* bhng  = (const float*)(ws + OFF_BHN);
    float* dtbuf = (float*)(ws + OFF_DT);

    const int t    = threadIdx.x;
    const int w    = t >> 6;
    const int l    = t & 63;
    const int l15  = l & 15;
    const int lq   = (l >> 4) & 3;
    const int lqh  = lq >> 1;
    const int c8   = (lq & 1) * 8;

    // ---- XCD-local self-assignment ----
    unsigned int xcc;
    asm volatile("s_getreg_b32 %0, hwreg(HW_REG_XCC_ID)" : "=s"(xcc));
    const int g = (int)(xcc & 7u);
    if (t == 0) {
        unsigned int* tk = (unsigned int*)(ws + OFF_CTR) + 2048 + g;
        s_slS = (int)(__hip_atomic_fetch_add(tk, 1u, __ATOMIC_RELAXED,
                                             __HIP_MEMORY_SCOPE_AGENT) & 31u);
    }
    __syncthreads();
    const int s_sl = s_slS;
    const int eb0  = g * 512 + s_sl * 16;

    unsigned int* stepslot  = (unsigned int*)(ws + OFF_CTR) + (size_t)g * 32;
    unsigned int* chunkslot = (unsigned int*)(ws + OFF_CTR + 4096) + (size_t)g * 32;

    const f32x4 fz = {0.f, 0.f, 0.f, 0.f};

    // ---- one-time init ----
    {
        const uint4* src = (const uint4*)(wgP + (size_t)s_sl * (24 * 3 * 64 * 8));
        uint4* dst = (uint4*)wgL;
        for (int i = t; i < 24 * 3 * 64; i += NTH) dst[i] = src[i];
    }
    {
        const uint4* src = (const uint4*)headP;
        uint4* dst = (uint4*)headL;
        for (int i = t; i < 16 * 64; i += NTH) dst[i] = src[i];
    }
    for (int idx = t; idx < 256; idx += NTH) { eb1L[idx] = enc_b1[idx]; eb2L[idx] = enc_b2[idx]; }
    for (int idx = t; idx < 64 * 32; idx += NTH) xbf64[idx >> 5][idx & 31] = 0;

    const float qb0 = q_b[0], qb1 = q_b[1], qb2 = q_b[2], qb3 = q_b[3];
    const float vb0 = v_b[0], vb1 = v_b[1], vb2 = v_b[2];
    const float cb0 = c_b[0], cb1 = c_b[1], cb2 = c_b[2];

    const int jd = s_sl * 16 + l15;
    const float bR  = bcmg[jd],        bZ  = bcmg[512 + jd];
    const float bIN = bcmg[1024 + jd], bHN = bhng[jd];
    const float wr2 = w256g[jd], wz2 = w256g[512 + jd], wn2 = w256g[1024 + jd];

    float ho[4][4];
    #pragma unroll
    for (int mt = 0; mt < 4; ++mt)
        #pragma unroll
        for (int i = 0; i < 4; ++i)
            ho[mt][i] = h0[(size_t)(g * 512 + w * 64 + mt * 16 + lq * 4 + i) * HID + jd];

    float dp0 = 0.f, dp1 = 0.f, dp2 = 0.f;
    f32x4 eReg[4][2];                      // E2 results held across shadow->cs0
    bool dead = false;
    __syncthreads();

    const size_t r0 = (size_t)(g * 512 + w * 64) + l15;

// ---- chunk staging: x -> xbf64/xownL/dtbuf, E1, E2 -> eReg ----
#define STAGE_CHUNK(cchunk)                                                          \
  { const int c_ = (cchunk);                                                         \
    for (int idx = t; idx < 17 * 16 * CHUNK; idx += NTH) {                           \
        int k = idx % 17, rem = idx / 17;                                            \
        int b = rem & 15, cc = rem >> 4;                                             \
        float v = x[((size_t)(eb0 + b) * T_STEPS + (c_ * 4 + cc)) * IN_DIM + k];     \
        xbf64[cc * 16 + b][k] = f2h(v);                                              \
        if (k < 3) xownL[c_ & 1][cc][b][k] = v;                                      \
        if (k == 16) {                                                               \
            dtbuf[(size_t)(eb0 + b) * 4 + cc] = v;                                   \
            xownL[c_ & 1][cc][b][3] = v;                                             \
        }                                                                            \
    }                                                                                \
    __syncthreads();                                                                 \
    { const int nt0 = 2 * w, nt1 = 2 * w + 1;                                        \
      half8 bv0 = *(const half8*)(w1P + ((size_t)nt0 * 64 + l) * 8);                 \
      half8 bv1 = *(const half8*)(w1P + ((size_t)nt1 * 64 + l) * 8);                 \
      f32x4 e1[4][2];                                                                \
      _Pragma("unroll")                                                              \
      for (int mt = 0; mt < 4; ++mt) {                                               \
          half8 av = *(const half8*)&xbf64[mt * 16 + l15][lq * 8];                   \
          e1[mt][0] = MFMA16(av, bv0, fz);                                           \
          e1[mt][1] = MFMA16(av, bv1, fz);                                           \
      }                                                                              \
      __syncthreads();                                                               \
      _Pragma("unroll")                                                              \
      for (int mt = 0; mt < 4; ++mt)                                                 \
          _Pragma("unroll")                                                          \
          for (int i = 0; i < 4; ++i) {                                              \
              int m64 = mt * 16 + lq * 4 + i;                                        \
              int n0 = nt0 * 16 + l15, n1 = nt1 * 16 + l15;                          \
              z1bf64[m64][n0] = f2h(fmaxf(e1[mt][0][i] + eb1L[n0], 0.f));            \
              z1bf64[m64][n1] = f2h(fmaxf(e1[mt][1][i] + eb1L[n1], 0.f));            \
          }                                                                          \
    }                                                                                \
    __syncthreads();                                                                 \
    { const int nt0 = 2 * w, nt1 = 2 * w + 1;                                        \
      _Pragma("unroll")                                                              \
      for (int mt = 0; mt < 4; ++mt) { eReg[mt][0] = fz; eReg[mt][1] = fz; }         \
      _Pragma("unroll")                                                              \
      for (int kt = 0; kt < 8; ++kt) {                                               \
          half8 bv0 = *(const half8*)(w2P + ((size_t)(nt0 * 8 + kt) * 64 + l) * 8);  \
          half8 bv1 = *(const half8*)(w2P + ((size_t)(nt1 * 8 + kt) * 64 + l) * 8);  \
          _Pragma("unroll")                                                          \
          for (int mt = 0; mt < 4; ++mt) {                                           \
              half8 av = *(const half8*)&z1bf64[mt * 16 + l15][kt * 32 + lq * 8];    \
              eReg[mt][0] = MFMA16(av, bv0, eReg[mt][0]);                            \
              eReg[mt][1] = MFMA16(av, bv1, eReg[mt][1]);                            \
          }                                                                          \
      }                                                                              \
    }                                                                                \
  }

#define LATWRITE()                                                                   \
  { const int nt0 = 2 * w, nt1 = 2 * w + 1;                                          \
    _Pragma("unroll")                                                                \
    for (int mt = 0; mt < 4; ++mt)                                                   \
        _Pragma("unroll")                                                            \
        for (int i = 0; i < 4; ++i) {                                                \
            int b = lq * 4 + i;                                                      \
            int n0 = nt0 * 16 + l15, n1 = nt1 * 16 + l15;                            \
            size_t rb = ((size_t)(eb0 + b) * 4 + mt) * 256;                          \
            latbuf[rb + n0] = f2h(fmaxf(eReg[mt][0][i] + eb2L[n0], 0.f));            \
            latbuf[rb + n1] = f2h(fmaxf(eReg[mt][1][i] + eb2L[n1], 0.f));            \
        } }

#define LDA_L(dst, ktv)                                                         \
            { _Pragma("unroll")                                                 \
              for (int mt = 0; mt < 4; ++mt)                                    \
                  dst[mt] = *(const half8*)(latp + (size_t)mt * (16 * 4 * 256) + (ktv) * 32); }
#define LDA_H(dst, ktv)                                                         \
            { _Pragma("unroll")                                                 \
              for (int mt = 0; mt < 4; ++mt)                                    \
                  dst[mt] = *(const half8*)(hA + (size_t)(ktv) * 16384 + mt * 256); }
#define LDB(dst, ktv)                                                           \
            { _Pragma("unroll")                                                 \
              for (int gg = 0; gg < 3; ++gg)                                    \
                  dst[gg] = *(const half8*)&wgL[(((ktv) * 3 + gg) * 64 + l) * 8]; }
#define DOMF_L(A, B)                                                            \
            { _Pragma("unroll")                                                 \
              for (int mt = 0; mt < 4; ++mt) {                                  \
                  aR[mt]  = MFMA16(A[mt], B[0], aR[mt]);                        \
                  aZ[mt]  = MFMA16(A[mt], B[1], aZ[mt]);                        \
                  aNi[mt] = MFMA16(A[mt], B[2], aNi[mt]); } }
#define DOMF_H(A, B)                                                            \
            { _Pragma("unroll")                                                 \
              for (int mt = 0; mt < 4; ++mt) {                                  \
                  aR[mt]  = MFMA16(A[mt], B[0], aR[mt]);                        \
                  aZ[mt]  = MFMA16(A[mt], B[1], aZ[mt]);                        \
                  aNh[mt] = MFMA16(A[mt], B[2], aNh[mt]); } }

    // ================= prologue: chunk 0 =================
    STAGE_CHUNK(0);
    LATWRITE();
    tag_arrive(chunkslot, s_sl, 1u);
    tag_wait(chunkslot, 1u);
    {
        const float* srcdt = dtbuf + (size_t)g * 2048;
        float* dstdt = &dtL[0][0];
        for (int idx = t; idx < 2048; idx += NTH) dstdt[idx] = srcdt[idx];
    }
    __syncthreads();

    for (int s = 0; s < T_STEPS; ++s) {
        const int cs = s & 3;
        const int rp = s & 1, wp = rp ^ 1;
        const unsigned short* hgx = hb[rp] + (size_t)g * 262144;
        unsigned short*       hwx = hb[wp] + (size_t)g * 262144 + (size_t)s_sl * 8192;

        // ===== cs==0 (s>0): full-group sync + publish shadow-computed chunk =====
        if (cs == 0 && s > 0) {
            const int c = s >> 2;
            tag_wait(stepslot, (unsigned int)s);       // all blocks done step s-1
            LATWRITE();                                // latbuf slots now free
            tag_arrive(chunkslot, s_sl, (unsigned int)(c + 1));
            tag_wait(chunkslot, (unsigned int)(c + 1));
            {
                const float* srcdt = dtbuf + (size_t)g * 2048;
                float* dstdt = &dtL[0][0];
                for (int idx = t; idx < 2048; idx += NTH) dstdt[idx] = srcdt[idx];
            }
            __syncthreads();
        }

        // ---- accumulators ----
        f32x4 aR[4], aZ[4], aNi[4], aNh[4];
        #pragma unroll
        for (int mt = 0; mt < 4; ++mt) { aR[mt] = fz; aZ[mt] = fz; aNi[mt] = fz; aNh[mt] = fz; }

        // ========== lat part (kt 0..7): chunk-stable, no gating ==========
        {
            const unsigned short* latp = latbuf + (r0 * 4 + cs) * 256 + lq * 8;
            half8 aF[3][4], bF[2][3];
            LDA_L(aF[0], 0); LDA_L(aF[1], 1); LDA_L(aF[2], 2);
            LDB(bF[0], 0); LDB(bF[1], 1);
            #pragma unroll
            for (int kt = 0; kt < 8; ++kt) {
                DOMF_L(aF[kt % 3], bF[kt & 1]);
                if (kt < 5) LDA_L(aF[kt % 3], kt + 3);
                if (kt < 6) LDB(bF[kt & 1], kt + 2);
            }
        }

        // ========== h part: per-slice producer-gated, staggered order ==========
        // One L1 invalidate per step; all h-line fills occur after tag observed.
        asm volatile("buffer_inv sc0" ::: "memory");
        {
            const unsigned short* hA = hgx + (size_t)lqh * 8192
                                           + (size_t)(w * 64 + l15) * 16 + c8;
            const int kt0 = s_sl >> 1;                 // stagger start 0..15
            half8 aH[2][4], bH[2][3];
            {
                int ka = kt0 & 15;
                slot_wait2(stepslot, 2 * ka, (unsigned int)s, &dead);
                LDA_H(aH[0], ka); LDB(bH[0], ka + 8);
                int kb = (kt0 + 1) & 15;
                slot_wait2(stepslot, 2 * kb, (unsigned int)s, &dead);
                LDA_H(aH[1], kb); LDB(bH[1], kb + 8);
            }
            for (int j = 0; j < 16; ++j) {
                const int cur = j & 1;
                int kn = 0;
                if (j < 14) {
                    kn = (kt0 + j + 2) & 15;
                    slot_wait2(stepslot, 2 * kn, (unsigned int)s, &dead);
                }
                DOMF_H(aH[cur], bH[cur]);
                if (j < 14) { LDA_H(aH[cur], kn); LDB(bH[cur], kn + 8); }
            }
        }

        // ---- gate nonlinearity + h_new write (slice-major, coalesced) ----
        // write-gate (everyone >= s-1) is implied: all 32 slots observed >= s above.
        #pragma unroll
        for (int mt = 0; mt < 4; ++mt) {
            #pragma unroll
            for (int i = 0; i < 4; ++i) {
                const int rl = w * 64 + mt * 16 + lq * 4 + i;
                float dtv = dtL[rl][cs];
                float gr = aR[mt][i]  + bR  + dtv * wr2;
                float gz = aZ[mt][i]  + bZ  + dtv * wz2;
                float gi = aNi[mt][i] + bIN + dtv * wn2;
                float gh = aNh[mt][i] + bHN;
                float r  = 1.f / (1.f + __expf(-gr));
                float zg = 1.f / (1.f + __expf(-gz));
                float narg = gi + r * gh;
                float n  = 1.f - 2.f / (__expf(2.f * narg) + 1.f);
                float hn = (1.f - zg) * n + zg * ho[mt][i];
                ho[mt][i] = hn;
                hwx[rl * 16 + l15] = f2h(hn);
            }
        }

        // ================= heads(s-1) + dp(s-1)  (AFTER h-write, BEFORE arrive)
        // h(s-1) lines are L1-fresh (filled post-tag during the h loop).
        if (s > 0) {
            f32x4 hc = fz;
            const int ka = 2 * w, kb = 2 * w + 1;
            const unsigned short* hH = hgx + (size_t)(s_sl * 16 + l15) * 16 + c8;
            half8 a0 = *(const half8*)(hH + (size_t)(2 * ka + lqh) * 8192);
            half8 b0 = *(const half8*)(headL + ((size_t)ka * 64 + l) * 8);
            half8 a1 = *(const half8*)(hH + (size_t)(2 * kb + lqh) * 8192);
            half8 b1 = *(const half8*)(headL + ((size_t)kb * 64 + l) * 8);
            hc = MFMA16(a0, b0, hc);
            hc = MFMA16(a1, b1, hc);
            #pragma unroll
            for (int i = 0; i < 4; ++i) sdotP[w][lq * 4 + i][l15] = hc[i];
            __syncthreads();
            if (t < 160) {                       // parallel 8-way reduce
                const int b = t / 10, d = t % 10;
                float acc = 0.f;
                #pragma unroll
                for (int w8 = 0; w8 < 8; ++w8) acc += sdotP[w8][b][d];
                sdS[b][d] = acc;
            }
            __syncthreads();
            if (t < BT) {
                const int b = t;
                const int ps = s - 1, pcc = ps & 3, ppar = (ps >> 2) & 1;
                float ax = xownL[ppar][pcc][b][0], ay = xownL[ppar][pcc][b][1];
                float az = xownL[ppar][pcc][b][2], dtv = xownL[ppar][pcc][b][3];
                float q0 = sdS[b][0] + qb0, q1 = sdS[b][1] + qb1;
                float q2 = sdS[b][2] + qb2, q3 = sdS[b][3] + qb3;
                float nrm = fmaxf(sqrtf(q0*q0 + q1*q1 + q2*q2 + q3*q3), 1e-12f);
                float qw = q0/nrm, qx = q1/nrm, qy = q2/nrm, qz = q3/nrm;
                float vx = sdS[b][4] + vb0, vy = sdS[b][5] + vb1, vz = sdS[b][6] + vb2;
                float ex = sdS[b][7] + cb0, ey = sdS[b][8] + cb1, ez = sdS[b][9] + cb2;
                float xx = qx*qx, yy = qy*qy, zz = qz*qz;
                float xy = qx*qy, xz = qx*qz, yz = qy*qz;
                float wxq = qw*qx, wyq = qw*qy, wzq = qw*qz;
                float aw0 = (1.f - 2.f*(yy+zz))*ax + 2.f*(xy-wzq)*ay + 2.f*(xz+wyq)*az;
                float aw1 = 2.f*(xy+wzq)*ax + (1.f - 2.f*(xx+zz))*ay + 2.f*(yz-wxq)*az;
                float aw2 = 2.f*(xz-wyq)*ax + 2.f*(yz+wxq)*ay + (1.f - 2.f*(xx+yy))*az;
                float hdt2 = 0.5f * dtv * dtv;
                dp0 += vx*dtv + aw0*hdt2 + ex;
                dp1 += vy*dtv + aw1*hdt2 + ey;
                dp2 += vz*dtv + aw2*hdt2 + ez;
            }
        }

        tag_arrive(stepslot, s_sl, (unsigned int)(s + 1));

        // ===== shadow: pre-compute NEXT chunk's encoder (x-only dep) =====
        if (cs == 3) {
            const int c = s >> 2;
            if (c + 1 < T_STEPS / CHUNK) STAGE_CHUNK(c + 1);
        }
    }
#undef LDA_L
#undef LDA_H
#undef LDB
#undef DOMF_L
#undef DOMF_H

    // ================= epilogue: heads(T-1) + dp(T-1) + store =================
    tag_wait(stepslot, (unsigned int)T_STEPS);
    {
        const unsigned short* hgx = hb[T_STEPS & 1] + (size_t)g * 262144;
        f32x4 hc = fz;
        const int ka = 2 * w, kb = 2 * w + 1;
        const unsigned short* hH = hgx + (size_t)(s_sl * 16 + l15) * 16 + c8;
        half8 a0 = *(const half8*)(hH + (size_t)(2 * ka + lqh) * 8192);
        half8 b0 = *(const half8*)(headL + ((size_t)ka * 64 + l) * 8);
        half8 a1 = *(const half8*)(hH + (size_t)(2 * kb + lqh) * 8192);
        half8 b1 = *(const half8*)(headL + ((size_t)kb * 64 + l) * 8);
        hc = MFMA16(a0, b0, hc);
        hc = MFMA16(a1, b1, hc);
        #pragma unroll
        for (int i = 0; i < 4; ++i) sdotP[w][lq * 4 + i][l15] = hc[i];
    }
    __syncthreads();
    if (t < BT) {
        const int b = t;
        float sd[10];
        #pragma unroll
        for (int d = 0; d < 10; ++d) {
            float acc = 0.f;
            #pragma unroll
            for (int w8 = 0; w8 < 8; ++w8) acc += sdotP[w8][b][d];
            sd[d] = acc;
        }
        const int pcc = (T_STEPS - 1) & 3, ppar = ((T_STEPS - 1) >> 2) & 1;
        float ax = xownL[ppar][pcc][b][0], ay = xownL[ppar][pcc][b][1];
        float az = xownL[ppar][pcc][b][2], dtv = xownL[ppar][pcc][b][3];
        float q0 = sd[0] + qb0, q1 = sd[1] + qb1;
        float q2 = sd[2] + qb2, q3 = sd[3] + qb3;
        float nrm = fmaxf(sqrtf(q0*q0 + q1*q1 + q2*q2 + q3*q3), 1e-12f);
        float qw = q0/nrm, qx = q1/nrm, qy = q2/nrm, qz = q3/nrm;
        float vx = sd[4] + vb0, vy = sd[5] + vb1, vz = sd[6] + vb2;
        float ex = sd[7] + cb0, ey = sd[8] + cb1, ez = sd[9] + cb2;
        float xx = qx*qx, yy = qy*qy, zz = qz*qz;
        float xy = qx*qy, xz = qx*qz, yz = qy*qz;
        float wxq = qw*qx, wyq = qw*qy, wzq = qw*qz;
        float aw0 = (1.f - 2.f*(yy+zz))*ax + 2.f*(xy-wzq)*ay + 2.f*(xz+wyq)*az;
        float aw1 = 2.f*(xy+wzq)*ax + (1.f - 2.f*(xx+zz))*ay + 2.f*(yz-wxq)*az;
        float aw2 = 2.f*(xz-wyq)*ax + 2.f*(yz+wxq)*ay + (1.f - 2.f*(xx+yy))*az;
        float hdt2 = 0.5f * dtv * dtv;
        dp0 += vx*dtv + aw0*hdt2 + ex;
        dp1 += vy*dtv + aw1*hdt2 + ey;
        dp2 += vz*dtv + aw2*hdt2 + ez;
        out[(size_t)(eb0 + b) * 3 + 0] = dp0;
        out[(size_t)(eb0 + b) * 3 + 1] = dp1;
        out[(size_t)(eb0 + b) * 3 + 2] = dp2;
    }
}

extern "C" void kernel_launch(void* const* d_in, const int* in_sizes, int n_in,
                              void* d_out, int out_size, void* d_ws, size_t ws_size,
                              hipStream_t stream) {
    const float* x      = (const float*)d_in[0];
    const float* h0     = (const float*)d_in[1];
    const float* enc_w1 = (const float*)d_in[2];
    const float* enc_b1 = (const float*)d_in[3];
    const float* enc_w2 = (const float*)d_in[4];
    const float* enc_b2 = (const float*)d_in[5];
    const float* w_ih   = (const float*)d_in[6];
    const float* w_hh   = (const float*)d_in[7];
    const float* b_ih   = (const float*)d_in[8];
    const float* b_hh   = (const float*)d_in[9];
    const float* q_w    = (const float*)d_in[10];
    const float* q_b    = (const float*)d_in[11];
    const float* v_w    = (const float*)d_in[12];
    const float* v_b    = (const float*)d_in[13];
    const float* c_w    = (const float*)d_in[14];
    const float* c_b    = (const float*)d_in[15];
    unsigned char* ws = (unsigned char*)d_ws;
    float* out = (float*)d_out;

    hipLaunchKernelGGL(pack_kernel, dim3(2048), dim3(256), 0, stream,
                       enc_w1, enc_w2, w_ih, w_hh, b_ih, b_hh, q_w, v_w, c_w, h0, ws);

    void* args[] = { (void*)&x, (void*)&h0, (void*)&enc_b1, (void*)&enc_b2,
                     (void*)&q_b, (void*)&v_b, (void*)&c_b, (void*)&ws, (void*)&out };
    (void)hipLaunchCooperativeKernel((void*)imu_coop_kernel, dim3(256), dim3(NTH),
                                     args, 0, stream);
}

// Round 10
// 12217.489 us; speedup vs baseline: 1.1242x; 1.1242x over previous
//
#include <hip/hip_runtime.h>
#include <math.h>

#define T_STEPS 512
#define IN_DIM  17
#define HID     512
#define LAT     256
#define BT      16
#define NTH     512
#define CHUNK   4

typedef __attribute__((ext_vector_type(8))) _Float16 half8;
typedef __attribute__((ext_vector_type(4))) float    f32x4;

// ---------------- workspace layout (byte offsets, 16B-aligned) ----------
// hbuf0/1 : h double buffer, SLICE-MAJOR: [8 g][32 ss][512 row][16] fp16
//           (each block owns contiguous 16KB per slice -> full-line writes
//            from ONE CU -> write-combine works -> lines stay in L2)
#define OFF_HB0   0
#define OFF_HB1   4194304
#define OFF_LAT   8388608
#define OFF_WG    16777216
#define OFF_W2P   19136512
#define OFF_W1P   19267584
#define OFF_HEADP 19283968
#define OFF_W256  19300352
#define OFF_BCOMB 19306496
#define OFF_BHN   19312640
#define OFF_DT    19314688
#define OFF_CTR   19380224
// ctr region: stepctr uint[8][512] + chunkctr uint[8][128] + ticket uint[8]

static __device__ inline unsigned short f2h(float f) {
    union { _Float16 h; unsigned short u; } cv;
    cv.h = (_Float16)f;
    return cv.u;
}

__global__ void pack_kernel(const float* __restrict__ enc_w1,
                            const float* __restrict__ enc_w2,
                            const float* __restrict__ w_ih,
                            const float* __restrict__ w_hh,
                            const float* __restrict__ b_ih,
                            const float* __restrict__ b_hh,
                            const float* __restrict__ q_w,
                            const float* __restrict__ v_w,
                            const float* __restrict__ c_w,
                            const float* __restrict__ h0,
                            unsigned char* __restrict__ ws) {
    unsigned short* wgP   = (unsigned short*)(ws + OFF_WG);
    unsigned short* w2P   = (unsigned short*)(ws + OFF_W2P);
    unsigned short* w1P   = (unsigned short*)(ws + OFF_W1P);
    unsigned short* headP = (unsigned short*)(ws + OFF_HEADP);
    unsigned short* hb0   = (unsigned short*)(ws + OFF_HB0);
    float* w256  = (float*)(ws + OFF_W256);
    float* bcomb = (float*)(ws + OFF_BCOMB);
    float* bhn   = (float*)(ws + OFF_BHN);
    unsigned int* ctr = (unsigned int*)(ws + OFF_CTR);

    const int tid = blockIdx.x * blockDim.x + threadIdx.x;
    const int stride = gridDim.x * blockDim.x;

    for (int idx = tid; idx < 32 * 24 * 3 * 64 * 8; idx += stride) {     // wgP
        int j = idx & 7, l = (idx >> 3) & 63;
        int r = idx >> 9;
        int g = r % 3; r /= 3;
        int kt = r % 24; int s = r / 24;
        int row = g * 512 + s * 16 + (l & 15);
        int kk  = ((l >> 4) & 3) * 8 + j;
        float v;
        if (kt < 8) v = w_ih[(size_t)row * 257 + (kt * 32 + kk)];
        else        v = w_hh[(size_t)row * 512 + ((kt - 8) * 32 + kk)];
        wgP[idx] = f2h(v);
    }
    for (int idx = tid; idx < 16 * 8 * 64 * 8; idx += stride) {          // w2P
        int j = idx & 7, l = (idx >> 3) & 63, kt = (idx >> 9) & 7, nt = idx >> 12;
        int n = nt * 16 + (l & 15);
        int k = kt * 32 + ((l >> 4) & 3) * 8 + j;
        w2P[idx] = f2h(enc_w2[(size_t)n * 256 + k]);
    }
    for (int idx = tid; idx < 16 * 64 * 8; idx += stride) {              // w1P
        int j = idx & 7, l = (idx >> 3) & 63, nt = idx >> 9;
        int n = nt * 16 + (l & 15);
        int k = ((l >> 4) & 3) * 8 + j;
        w1P[idx] = (k < IN_DIM) ? f2h(enc_w1[(size_t)n * IN_DIM + k]) : (unsigned short)0;
    }
    for (int idx = tid; idx < 16 * 64 * 8; idx += stride) {              // headP
        int j = idx & 7, l = (idx >> 3) & 63, kt = idx >> 9;
        int d = l & 15;
        int k = kt * 32 + ((l >> 4) & 3) * 8 + j;
        float v = 0.f;
        if (d < 4)       v = q_w[(size_t)d * HID + k];
        else if (d < 7)  v = v_w[(size_t)(d - 4) * HID + k];
        else if (d < 10) v = c_w[(size_t)(d - 7) * HID + k];
        headP[idx] = f2h(v);
    }
    for (int idx = tid; idx < 1536; idx += stride) {
        w256[idx]  = w_ih[(size_t)idx * 257 + 256];
        bcomb[idx] = (idx < 1024) ? (b_ih[idx] + b_hh[idx]) : b_ih[idx];
    }
    for (int idx = tid; idx < 512; idx += stride) bhn[idx] = b_hh[1024 + idx];
    for (int idx = tid; idx < 4096 * 512; idx += stride) {               // h0 -> hbuf0 (slice-major)
        int c  = idx & 15;
        int r  = (idx >> 4) & 511;
        int sg = idx >> 13;            // g*32 + ss
        int gg = sg >> 5, ss = sg & 31;
        hb0[idx] = f2h(h0[((size_t)(gg * 512 + r)) * 512 + ss * 16 + c]);
    }
    for (int idx = tid; idx < 5128; idx += stride) ctr[idx] = 0;         // barriers + tickets
}

#define MFMA16(a, b, c) __builtin_amdgcn_mfma_f32_16x16x32_f16((a), (b), (c), 0, 0, 0)

// ---- split 32-block XCD-local barrier: arrive (non-blocking) / wait ----
// Groups are pinned to one physical XCD (g = HW_REG_XCC_ID), so the XCD L2 is
// the coherence point. arrive: __syncthreads drains all waves' stores to L2,
// then one relaxed agent-scope add. wait: poll relaxed, then L1-only inv.
// Watchdog: a genuine deadlock breaks out after ~1e8 spins so the run FINISHES
// (wrong) and yields diagnostics instead of killing the container.
static __device__ inline void bar_arrive(unsigned int* slot) {
    __syncthreads();
    if (threadIdx.x == 0)
        __hip_atomic_fetch_add(slot, 1u, __ATOMIC_RELAXED, __HIP_MEMORY_SCOPE_AGENT);
}
static __device__ inline void bar_wait(unsigned int* slot) {
    if (threadIdx.x == 0) {
        unsigned int spins = 0;
        while (__hip_atomic_load(slot, __ATOMIC_RELAXED, __HIP_MEMORY_SCOPE_AGENT) < 32u) {
            __builtin_amdgcn_s_sleep(2);
            if (++spins > 100000000u) break;   // watchdog: never hit in normal runs
        }
    }
    __syncthreads();
    asm volatile("buffer_inv sc0" ::: "memory");   // per-wave L1 invalidate
}
static __device__ inline void xcd_barrier(unsigned int* slot) {
    bar_arrive(slot);
    bar_wait(slot);
}

__global__ __launch_bounds__(NTH, 2)
void imu_coop_kernel(const float* __restrict__ x,
                     const float* __restrict__ h0,
                     const float* __restrict__ enc_b1,
                     const float* __restrict__ enc_b2,
                     const float* __restrict__ q_b,
                     const float* __restrict__ v_b,
                     const float* __restrict__ c_b,
                     unsigned char* __restrict__ ws,
                     float* __restrict__ out)
{
    __shared__ __align__(16) unsigned short wgL[24 * 3 * 64 * 8];   // 73,728 B
    __shared__ __align__(16) unsigned short headL[16 * 64 * 8];     // 16,384 B
    __shared__ __align__(16) unsigned short xbf64[64][32];          //  4,096 B
    __shared__ __align__(16) unsigned short z1bf64[64][264];        // 33,792 B
    __shared__ __align__(16) float          sdotP[8][16][17];       //  8,704 B
    __shared__ float eb1L[256], eb2L[256];                          //  2,048 B
    __shared__ float dtL[512][4];                                   //  8,192 B
    __shared__ float xownL[2][4][16][4];                            //  2,048 B
    __shared__ int   s_slS;

    unsigned short* hb[2] = { (unsigned short*)(ws + OFF_HB0),
                              (unsigned short*)(ws + OFF_HB1) };
    unsigned short*       latbuf = (unsigned short*)(ws + OFF_LAT);
    const unsigned short* wgP    = (const unsigned short*)(ws + OFF_WG);
    const unsigned short* w2P    = (const unsigned short*)(ws + OFF_W2P);
    const unsigned short* w1P    = (const unsigned short*)(ws + OFF_W1P);
    const unsigned short* headP  = (const unsigned short*)(ws + OFF_HEADP);
    const float* w256g = (const float*)(ws + OFF_W256);
    const float* bcmg  = (const float*)(ws + OFF_BCOMB);
    const float* bhng  = (const float*)(ws + OFF_BHN);
    float* dtbuf = (float*)(ws + OFF_DT);

    const int t    = threadIdx.x;
    const int w    = t >> 6;
    const int l    = t & 63;
    const int l15  = l & 15;
    const int lq   = (l >> 4) & 3;
    const int lqh  = lq >> 1;            // which of the two 16-col slices in a 32-K tile
    const int c8   = (lq & 1) * 8;       // col offset inside the slice

    // ---- XCD-local self-assignment: group = physical XCD, slice = ticket ----
    // LDS ~149KB forces 1 block/CU; cooperative launch co-residency on 256 CUs
    // => exactly 32 blocks per XCD, so tickets 0..31 and groups are XCD-local
    // BY CONSTRUCTION (no assumption about blockIdx->XCD mapping).
    unsigned int xcc;
    asm volatile("s_getreg_b32 %0, hwreg(HW_REG_XCC_ID)" : "=s"(xcc));
    const int g = (int)(xcc & 7u);
    if (t == 0) {
        unsigned int* tk = (unsigned int*)(ws + OFF_CTR) + 5120 + g;
        s_slS = (int)(__hip_atomic_fetch_add(tk, 1u, __ATOMIC_RELAXED,
                                             __HIP_MEMORY_SCOPE_AGENT) & 31u);
    }
    __syncthreads();
    const int s_sl = s_slS;                      // gate N-slice 0..31
    const int eb0  = g * 512 + s_sl * 16;        // encoder/heads batch rows

    unsigned int* stepctr  = (unsigned int*)(ws + OFF_CTR) + (size_t)g * 512;
    unsigned int* chunkctr = (unsigned int*)(ws + OFF_CTR + 16384) + (size_t)g * 128;

    const f32x4 fz = {0.f, 0.f, 0.f, 0.f};

    // ---- one-time init ----
    {
        const uint4* src = (const uint4*)(wgP + (size_t)s_sl * (24 * 3 * 64 * 8));
        uint4* dst = (uint4*)wgL;
        for (int i = t; i < 24 * 3 * 64; i += NTH) dst[i] = src[i];
    }
    {
        const uint4* src = (const uint4*)headP;
        uint4* dst = (uint4*)headL;
        for (int i = t; i < 16 * 64; i += NTH) dst[i] = src[i];
    }
    for (int idx = t; idx < 256; idx += NTH) { eb1L[idx] = enc_b1[idx]; eb2L[idx] = enc_b2[idx]; }
    for (int idx = t; idx < 64 * 32; idx += NTH) xbf64[idx >> 5][idx & 31] = 0;

    const float qb0 = q_b[0], qb1 = q_b[1], qb2 = q_b[2], qb3 = q_b[3];
    const float vb0 = v_b[0], vb1 = v_b[1], vb2 = v_b[2];
    const float cb0 = c_b[0], cb1 = c_b[1], cb2 = c_b[2];

    const int jd = s_sl * 16 + l15;              // owned gate/h dim
    const float bR  = bcmg[jd],        bZ  = bcmg[512 + jd];
    const float bIN = bcmg[1024 + jd], bHN = bhng[jd];
    const float wr2 = w256g[jd], wz2 = w256g[512 + jd], wn2 = w256g[1024 + jd];

    float ho[4][4];                              // h_old fp32 in regs
    #pragma unroll
    for (int mt = 0; mt < 4; ++mt)
        #pragma unroll
        for (int i = 0; i < 4; ++i)
            ho[mt][i] = h0[(size_t)(g * 512 + w * 64 + mt * 16 + lq * 4 + i) * HID + jd];

    float dp0 = 0.f, dp1 = 0.f, dp2 = 0.f;
    __syncthreads();

    const size_t r0 = (size_t)(g * 512 + w * 64) + l15;   // latbuf A-frag row base

#define LDA_L(dst, ktv)                                                         \
            { _Pragma("unroll")                                                 \
              for (int mt = 0; mt < 4; ++mt)                                    \
                  dst[mt] = *(const half8*)(latp + (size_t)mt * (16 * 4 * 256) + (ktv) * 32); }
#define LDA_H(dst, ktv)                                                         \
            { _Pragma("unroll")                                                 \
              for (int mt = 0; mt < 4; ++mt)                                    \
                  dst[mt] = *(const half8*)(hA + (size_t)((ktv) - 8) * 16384 + mt * 256); }
#define LDB(dst, ktv)                                                           \
            { _Pragma("unroll")                                                 \
              for (int gg = 0; gg < 3; ++gg)                                    \
                  dst[gg] = *(const half8*)&wgL[(((ktv) * 3 + gg) * 64 + l) * 8]; }
#define DOMF_L(A, B)                                                            \
            { _Pragma("unroll")                                                 \
              for (int mt = 0; mt < 4; ++mt) {                                  \
                  aR[mt]  = MFMA16(A[mt], B[0], aR[mt]);                        \
                  aZ[mt]  = MFMA16(A[mt], B[1], aZ[mt]);                        \
                  aNi[mt] = MFMA16(A[mt], B[2], aNi[mt]); } }
#define DOMF_H(A, B)                                                            \
            { _Pragma("unroll")                                                 \
              for (int mt = 0; mt < 4; ++mt) {                                  \
                  aR[mt]  = MFMA16(A[mt], B[0], aR[mt]);                        \
                  aZ[mt]  = MFMA16(A[mt], B[1], aZ[mt]);                        \
                  aNh[mt] = MFMA16(A[mt], B[2], aNh[mt]); } }

    for (int s = 0; s < T_STEPS; ++s) {
        const int cs = s & 3;
        const int rp = s & 1, wp = rp ^ 1;
        const unsigned short* hgx = hb[rp] + (size_t)g * 262144;              // read base
        unsigned short*       hwx = hb[wp] + (size_t)g * 262144 + (size_t)s_sl * 8192;

        // ================= chunk pre-phase, once per 4 steps =================
        if (cs == 0) {
            // must wait for step s-1 BEFORE overwriting latbuf/dtbuf slots
            if (s > 0) bar_wait(&stepctr[s - 1]);
            const int c = s >> 2;
            for (int idx = t; idx < 17 * 16 * CHUNK; idx += NTH) {
                int k = idx % 17, rem = idx / 17;
                int b = rem & 15, cc = rem >> 4;
                float v = x[((size_t)(eb0 + b) * T_STEPS + (c * 4 + cc)) * IN_DIM + k];
                xbf64[cc * 16 + b][k] = f2h(v);
                if (k < 3) xownL[c & 1][cc][b][k] = v;
                if (k == 16) {
                    dtbuf[(size_t)(eb0 + b) * 4 + cc] = v;
                    xownL[c & 1][cc][b][3] = v;
                }
            }
            __syncthreads();
            {   // E1: M=64 (16 batch x 4 steps), N=256, K=32
                const int nt0 = 2 * w, nt1 = 2 * w + 1;
                half8 bv0 = *(const half8*)(w1P + ((size_t)nt0 * 64 + l) * 8);
                half8 bv1 = *(const half8*)(w1P + ((size_t)nt1 * 64 + l) * 8);
                f32x4 e[4][2];
                #pragma unroll
                for (int mt = 0; mt < 4; ++mt) {
                    half8 av = *(const half8*)&xbf64[mt * 16 + l15][lq * 8];
                    e[mt][0] = MFMA16(av, bv0, fz);
                    e[mt][1] = MFMA16(av, bv1, fz);
                }
                __syncthreads();
                #pragma unroll
                for (int mt = 0; mt < 4; ++mt)
                    #pragma unroll
                    for (int i = 0; i < 4; ++i) {
                        int m64 = mt * 16 + lq * 4 + i;
                        int n0 = nt0 * 16 + l15, n1 = nt1 * 16 + l15;
                        z1bf64[m64][n0] = f2h(fmaxf(e[mt][0][i] + eb1L[n0], 0.f));
                        z1bf64[m64][n1] = f2h(fmaxf(e[mt][1][i] + eb1L[n1], 0.f));
                    }
            }
            __syncthreads();
            {   // E2: M=64, N=256, K=256 -> latbuf (global)
                const int nt0 = 2 * w, nt1 = 2 * w + 1;
                f32x4 e[4][2];
                #pragma unroll
                for (int mt = 0; mt < 4; ++mt) { e[mt][0] = fz; e[mt][1] = fz; }
                #pragma unroll
                for (int kt = 0; kt < 8; ++kt) {
                    half8 bv0 = *(const half8*)(w2P + ((size_t)(nt0 * 8 + kt) * 64 + l) * 8);
                    half8 bv1 = *(const half8*)(w2P + ((size_t)(nt1 * 8 + kt) * 64 + l) * 8);
                    #pragma unroll
                    for (int mt = 0; mt < 4; ++mt) {
                        half8 av = *(const half8*)&z1bf64[mt * 16 + l15][kt * 32 + lq * 8];
                        e[mt][0] = MFMA16(av, bv0, e[mt][0]);
                        e[mt][1] = MFMA16(av, bv1, e[mt][1]);
                    }
                }
                #pragma unroll
                for (int mt = 0; mt < 4; ++mt)
                    #pragma unroll
                    for (int i = 0; i < 4; ++i) {
                        int b = lq * 4 + i;      // batch-in-16 ; cc = mt
                        int n0 = nt0 * 16 + l15, n1 = nt1 * 16 + l15;
                        size_t rb = ((size_t)(eb0 + b) * 4 + mt) * 256;
                        latbuf[rb + n0] = f2h(fmaxf(e[mt][0][i] + eb2L[n0], 0.f));
                        latbuf[rb + n1] = f2h(fmaxf(e[mt][1][i] + eb2L[n1], 0.f));
                    }
            }
            xcd_barrier(&chunkctr[c]);
            {   // stage whole group's dt for this chunk into LDS (coalesced)
                const float* srcdt = dtbuf + (size_t)g * 2048;
                float* dstdt = &dtL[0][0];
                for (int idx = t; idx < 2048; idx += NTH) dstdt[idx] = srcdt[idx];
            }
            __syncthreads();
        }

        // ---- accumulators ----
        f32x4 aR[4], aZ[4], aNi[4], aNh[4];
        #pragma unroll
        for (int mt = 0; mt < 4; ++mt) { aR[mt] = fz; aZ[mt] = fz; aNi[mt] = fz; aNh[mt] = fz; }

        // ========== lat part of gate GEMM (kt 0..7): chunk-stable, no h dep ==========
        {
            const unsigned short* latp = latbuf + (r0 * 4 + cs) * 256 + lq * 8;
            half8 aF[3][4], bF[2][3];
            LDA_L(aF[0], 0); LDA_L(aF[1], 1); LDA_L(aF[2], 2);
            LDB(bF[0], 0); LDB(bF[1], 1);
            #pragma unroll
            for (int kt = 0; kt < 8; ++kt) {
                DOMF_L(aF[kt % 3], bF[kt & 1]);
                if (kt < 5) LDA_L(aF[kt % 3], kt + 3);
                if (kt < 6) LDB(bF[kt & 1], kt + 2);
            }
        }

        // ========== wait for h(s-1) (absorbs skew under the lat work above) ==========
        if (cs != 0 && s > 0) bar_wait(&stepctr[s - 1]);

        // ---- h-part prologue: issue depth-3 A loads so they fly under heads ----
        const unsigned short* hA = hgx + (size_t)lqh * 8192
                                       + (size_t)(w * 64 + l15) * 16 + c8;
        half8 aF[3][4], bF[2][3];
        LDA_H(aF[0], 8); LDA_H(aF[1], 9); LDA_H(aF[2], 10);
        LDB(bF[0], 8); LDB(bF[1], 9);

        // ================= heads(s-1) + dp(s-1) =================
        if (s > 0) {
            f32x4 hc = fz;
            const int ka = 2 * w, kb = 2 * w + 1;
            const unsigned short* hH = hgx + (size_t)(s_sl * 16 + l15) * 16 + c8;
            half8 a0 = *(const half8*)(hH + (size_t)(2 * ka + lqh) * 8192);
            half8 b0 = *(const half8*)(headL + ((size_t)ka * 64 + l) * 8);
            half8 a1 = *(const half8*)(hH + (size_t)(2 * kb + lqh) * 8192);
            half8 b1 = *(const half8*)(headL + ((size_t)kb * 64 + l) * 8);
            hc = MFMA16(a0, b0, hc);
            hc = MFMA16(a1, b1, hc);
            #pragma unroll
            for (int i = 0; i < 4; ++i) sdotP[w][lq * 4 + i][l15] = hc[i];
            __syncthreads();
            if (t < BT) {
                const int b = t;
                float sd[10];
                #pragma unroll
                for (int d = 0; d < 10; ++d) {
                    float acc = 0.f;
                    #pragma unroll
                    for (int w8 = 0; w8 < 8; ++w8) acc += sdotP[w8][b][d];
                    sd[d] = acc;
                }
                const int ps = s - 1, pcc = ps & 3, ppar = (ps >> 2) & 1;
                float ax = xownL[ppar][pcc][b][0], ay = xownL[ppar][pcc][b][1];
                float az = xownL[ppar][pcc][b][2], dtv = xownL[ppar][pcc][b][3];
                float q0 = sd[0] + qb0, q1 = sd[1] + qb1;
                float q2 = sd[2] + qb2, q3 = sd[3] + qb3;
                float nrm = fmaxf(sqrtf(q0*q0 + q1*q1 + q2*q2 + q3*q3), 1e-12f);
                float qw = q0/nrm, qx = q1/nrm, qy = q2/nrm, qz = q3/nrm;
                float vx = sd[4] + vb0, vy = sd[5] + vb1, vz = sd[6] + vb2;
                float ex = sd[7] + cb0, ey = sd[8] + cb1, ez = sd[9] + cb2;
                float xx = qx*qx, yy = qy*qy, zz = qz*qz;
                float xy = qx*qy, xz = qx*qz, yz = qy*qz;
                float wxq = qw*qx, wyq = qw*qy, wzq = qw*qz;
                float aw0 = (1.f - 2.f*(yy+zz))*ax + 2.f*(xy-wzq)*ay + 2.f*(xz+wyq)*az;
                float aw1 = 2.f*(xy+wzq)*ax + (1.f - 2.f*(xx+zz))*ay + 2.f*(yz-wxq)*az;
                float aw2 = 2.f*(xz-wyq)*ax + 2.f*(yz+wxq)*ay + (1.f - 2.f*(xx+yy))*az;
                float hdt2 = 0.5f * dtv * dtv;
                dp0 += vx*dtv + aw0*hdt2 + ex;
                dp1 += vy*dtv + aw1*hdt2 + ey;
                dp2 += vz*dtv + aw2*hdt2 + ez;
            }
        }

        // ========== h part of gate GEMM (kt 8..23) ==========
        #pragma unroll
        for (int k2 = 0; k2 < 16; ++k2) {
            DOMF_H(aF[k2 % 3], bF[k2 & 1]);
            if (k2 < 13) LDA_H(aF[k2 % 3], k2 + 11);
            if (k2 < 14) LDB(bF[k2 & 1], k2 + 10);
        }

        // ---- gate nonlinearity + h_new write (slice-major, coalesced) ----
        #pragma unroll
        for (int mt = 0; mt < 4; ++mt) {
            #pragma unroll
            for (int i = 0; i < 4; ++i) {
                const int rl = w * 64 + mt * 16 + lq * 4 + i;   // row in group
                float dtv = dtL[rl][cs];
                float gr = aR[mt][i]  + bR  + dtv * wr2;
                float gz = aZ[mt][i]  + bZ  + dtv * wz2;
                float gi = aNi[mt][i] + bIN + dtv * wn2;
                float gh = aNh[mt][i] + bHN;
                float r  = 1.f / (1.f + __expf(-gr));
                float zg = 1.f / (1.f + __expf(-gz));
                float narg = gi + r * gh;
                float n  = 1.f - 2.f / (__expf(2.f * narg) + 1.f);
                float hn = (1.f - zg) * n + zg * ho[mt][i];
                ho[mt][i] = hn;
                hwx[rl * 16 + l15] = f2h(hn);
            }
        }
        bar_arrive(&stepctr[s]);
    }
#undef LDA_L
#undef LDA_H
#undef LDB
#undef DOMF_L
#undef DOMF_H

    // ================= epilogue: heads(T-1) + dp(T-1) + store =================
    bar_wait(&stepctr[T_STEPS - 1]);
    {
        const unsigned short* hgx = hb[T_STEPS & 1] + (size_t)g * 262144;
        f32x4 hc = fz;
        const int ka = 2 * w, kb = 2 * w + 1;
        const unsigned short* hH = hgx + (size_t)(s_sl * 16 + l15) * 16 + c8;
        half8 a0 = *(const half8*)(hH + (size_t)(2 * ka + lqh) * 8192);
        half8 b0 = *(const half8*)(headL + ((size_t)ka * 64 + l) * 8);
        half8 a1 = *(const half8*)(hH + (size_t)(2 * kb + lqh) * 8192);
        half8 b1 = *(const half8*)(headL + ((size_t)kb * 64 + l) * 8);
        hc = MFMA16(a0, b0, hc);
        hc = MFMA16(a1, b1, hc);
        #pragma unroll
        for (int i = 0; i < 4; ++i) sdotP[w][lq * 4 + i][l15] = hc[i];
    }
    __syncthreads();
    if (t < BT) {
        const int b = t;
        float sd[10];
        #pragma unroll
        for (int d = 0; d < 10; ++d) {
            float acc = 0.f;
            #pragma unroll
            for (int w8 = 0; w8 < 8; ++w8) acc += sdotP[w8][b][d];
            sd[d] = acc;
        }
        const int pcc = (T_STEPS - 1) & 3, ppar = ((T_STEPS - 1) >> 2) & 1;
        float ax = xownL[ppar][pcc][b][0], ay = xownL[ppar][pcc][b][1];
        float az = xownL[ppar][pcc][b][2], dtv = xownL[ppar][pcc][b][3];
        float q0 = sd[0] + qb0, q1 = sd[1] + qb1;
        float q2 = sd[2] + qb2, q3 = sd[3] + qb3;
        float nrm = fmaxf(sqrtf(q0*q0 + q1*q1 + q2*q2 + q3*q3), 1e-12f);
        float qw = q0/nrm, qx = q1/nrm, qy = q2/nrm, qz = q3/nrm;
        float vx = sd[4] + vb0, vy = sd[5] + vb1, vz = sd[6] + vb2;
        float ex = sd[7] + cb0, ey = sd[8] + cb1, ez = sd[9] + cb2;
        float xx = qx*qx, yy = qy*qy, zz = qz*qz;
        float xy = qx*qy, xz = qx*qz, yz = qy*qz;
        float wxq = qw*qx, wyq = qw*qy, wzq = qw*qz;
        float aw0 = (1.f - 2.f*(yy+zz))*ax + 2.f*(xy-wzq)*ay + 2.f*(xz+wyq)*az;
        float aw1 = 2.f*(xy+wzq)*ax + (1.f - 2.f*(xx+zz))*ay + 2.f*(yz-wxq)*az;
        float aw2 = 2.f*(xz-wyq)*ax + 2.f*(yz+wxq)*ay + (1.f - 2.f*(xx+yy))*az;
        float hdt2 = 0.5f * dtv * dtv;
        dp0 += vx*dtv + aw0*hdt2 + ex;
        dp1 += vy*dtv + aw1*hdt2 + ey;
        dp2 += vz*dtv + aw2*hdt2 + ez;
        out[(size_t)(eb0 + b) * 3 + 0] = dp0;
        out[(size_t)(eb0 + b) * 3 + 1] = dp1;
        out[(size_t)(eb0 + b) * 3 + 2] = dp2;
    }
}

extern "C" void kernel_launch(void* const* d_in, const int* in_sizes, int n_in,
                              void* d_out, int out_size, void* d_ws, size_t ws_size,
                              hipStream_t stream) {
    const float* x      = (const float*)d_in[0];
    const float* h0     = (const float*)d_in[1];
    const float* enc_w1 = (const float*)d_in[2];
    const float* enc_b1 = (const float*)d_in[3];
    const float* enc_w2 = (const float*)d_in[4];
    const float* enc_b2 = (const float*)d_in[5];
    const float* w_ih   = (const float*)d_in[6];
    const float* w_hh   = (const float*)d_in[7];
    const float* b_ih   = (const float*)d_in[8];
    const float* b_hh   = (const float*)d_in[9];
    const float* q_w    = (const float*)d_in[10];
    const float* q_b    = (const float*)d_in[11];
    const float* v_w    = (const float*)d_in[12];
    const float* v_b    = (const float*)d_in[13];
    const float* c_w    = (const float*)d_in[14];
    const float* c_b    = (const float*)d_in[15];
    unsigned char* ws = (unsigned char*)d_ws;
    float* out = (float*)d_out;

    hipLaunchKernelGGL(pack_kernel, dim3(2048), dim3(256), 0, stream,
                       enc_w1, enc_w2, w_ih, w_hh, b_ih, b_hh, q_w, v_w, c_w, h0, ws);

    void* args[] = { (void*)&x, (void*)&h0, (void*)&enc_b1, (void*)&enc_b2,
                     (void*)&q_b, (void*)&v_b, (void*)&c_b, (void*)&ws, (void*)&out };
    (void)hipLaunchCooperativeKernel((void*)imu_coop_kernel, dim3(256), dim3(NTH),
                                     args, 0, stream);
}